// Round 10
// baseline (251.925 us; speedup 1.0000x reference)
//
#include <hip/hip_runtime.h>

#define N_NODES 8192
#define N_EDGES 262144
#define D 256
#define ADJ_WORDS 256     // 8192 bits per row / 32
#define MAX_DEG 128       // Poisson(33): P(deg>128) ~ 1e-40
#define AGG_BLOCKS 2048   // 4 waves/block, ONE row per wave -> 8192 waves, 8/SIMD
#define RED_BLOCKS 128    // partial-reduction stage-1 blocks (2048 -> 128 rows)

typedef __attribute__((ext_vector_type(8))) short bf16x8;
typedef __attribute__((ext_vector_type(4))) float f32x4;

__device__ __forceinline__ short f2bf(float f) {
    unsigned u = __builtin_bit_cast(unsigned, f);
    u += 0x7fffu + ((u >> 16) & 1);   // round to nearest even
    return (short)(u >> 16);
}
__device__ __forceinline__ float bf2f(unsigned short u) {
    return __builtin_bit_cast(float, ((unsigned)u) << 16);
}

// ---------------- adjacency build: set-semantics bitmask + exact degree ----------------
__global__ void build_adj(const int* __restrict__ ei, unsigned* __restrict__ adj,
                          int* __restrict__ deg) {
    int i = blockIdx.x * blockDim.x + threadIdx.x;
    int r, c;
    if (i < N_EDGES) {
        r = ei[i];
        c = ei[N_EDGES + i];
    } else if (i < N_EDGES + N_NODES) {
        r = i - N_EDGES;          // self loop
        c = r;
    } else {
        return;
    }
    unsigned bit = 1u << (c & 31);
    unsigned old = atomicOr(&adj[r * ADJ_WORDS + (c >> 5)], bit);
    if (!(old & bit)) atomicAdd(&deg[r], 1);   // count only newly-set bits (set semantics)
}

// ------- bitmask -> neighbor list (idx + weight, dinv inline); tail blocks: W->bf16 -------
__global__ __launch_bounds__(256) void build_nbrs(const unsigned* __restrict__ adj,
                                                  const int* __restrict__ deg,
                                                  int* __restrict__ nbr_idx,
                                                  float* __restrict__ nbr_w,
                                                  const float* __restrict__ W1,
                                                  const float* __restrict__ W2,
                                                  const float* __restrict__ W3,
                                                  unsigned short* __restrict__ Wb1,
                                                  unsigned short* __restrict__ Wb2,
                                                  unsigned short* __restrict__ Wb3) {
    if (blockIdx.x >= N_NODES) {   // weight-conversion tail blocks
        int i = (blockIdx.x - N_NODES) * 256 + threadIdx.x;
        int which = i >> 16, j = i & 65535;
        const float* src = which == 0 ? W1 : which == 1 ? W2 : W3;
        unsigned short* dst = which == 0 ? Wb1 : which == 1 ? Wb2 : Wb3;
        dst[j] = (unsigned short)f2bf(src[j]);
        return;
    }
    const int r = blockIdx.x;
    const int t = threadIdx.x;
    const int lane = t & 63, wave = t >> 6;
    unsigned m = adj[r * ADJ_WORDS + t];
    int cnt = __popc(m);
    int x = cnt;
    #pragma unroll
    for (int off = 1; off < 64; off <<= 1) {
        int v = __shfl_up(x, off, 64);
        if (lane >= off) x += v;
    }
    __shared__ int wtot[4];
    if (lane == 63) wtot[wave] = x;
    __syncthreads();
    int woff = 0;
    #pragma unroll
    for (int w = 0; w < 4; w++) woff += (w < wave) ? wtot[w] : 0;
    int base = woff + x - cnt;       // exclusive prefix
    const float dr = rsqrtf((float)deg[r]);   // deg >= 1 (self loop)
    int* oi = nbr_idx + (size_t)r * MAX_DEG;
    float* ow = nbr_w + (size_t)r * MAX_DEG;
    while (m) {
        int b = __ffs(m) - 1;
        m &= m - 1;
        int c = (t << 5) + b;
        if (base < MAX_DEG) {
            oi[base] = c;
            ow[base] = dr * rsqrtf((float)deg[c]);
        }
        base++;
    }
}

// -------- Hb(bf16) = bnapply(X) @ W^T + b  (MFMA 16x16x32 bf16) --------
// BN finalize folded in (APPLY): blocks reduce psum2/psq2 (128 rows, prev dispatch)
// -> scale/shift in LDS. XBF16: X is bf16 (inter-layer Gb). 64-row M-tile, 512 blocks.
template <bool APPLY, bool RELU, bool XBF16>
__global__ __launch_bounds__(256) void gemm_mfma(const void* __restrict__ Xsrc,
                                                 const float* __restrict__ psum2,
                                                 const float* __restrict__ psq2,
                                                 const float* __restrict__ g,
                                                 const float* __restrict__ be,
                                                 const unsigned short* __restrict__ Wb,
                                                 const float* __restrict__ bias,
                                                 unsigned short* __restrict__ Hb) {
    __shared__ float ssc[256], ssh[256];
    const int tid = threadIdx.x;
    if (APPLY) {
        float s = 0.f, q = 0.f;
        #pragma unroll 8
        for (int i = 0; i < RED_BLOCKS; i++) {
            s += psum2[i * 256 + tid];
            q += psq2[i * 256 + tid];
        }
        float mu = s * (1.0f / N_NODES);
        float var = q * (1.0f / N_NODES) - mu * mu;
        float rstd = rsqrtf(var + 1e-5f);
        float sc = g[tid] * rstd;
        ssc[tid] = sc;
        ssh[tid] = be[tid] - mu * sc;
        __syncthreads();
    }

    const int bn = blockIdx.x * 64;           // output-channel tile
    const int bm = blockIdx.y * 64;           // node tile (64 rows, 16/wave)
    const int wave = tid >> 6, lane = tid & 63;
    const int l16 = lane & 15, q = lane >> 4;
    const int mrow = bm + wave * 16 + l16;    // this lane's X row

    f32x4 acc[4];
    #pragma unroll
    for (int j = 0; j < 4; j++) acc[j] = (f32x4){0.f, 0.f, 0.f, 0.f};

    for (int k0 = 0; k0 < D; k0 += 32) {
        const int kq = k0 + q * 8;
        bf16x8 xb;
        float v[8];
        if (XBF16) {
            bf16x8 xr = *(const bf16x8*)((const unsigned short*)Xsrc + (size_t)mrow * D + kq);
            #pragma unroll
            for (int j = 0; j < 8; j++) v[j] = bf2f((unsigned short)xr[j]);
        } else {
            const float* xr = (const float*)Xsrc + (size_t)mrow * D + kq;
            float4 a = *(const float4*)xr;
            float4 b = *(const float4*)(xr + 4);
            v[0] = a.x; v[1] = a.y; v[2] = a.z; v[3] = a.w;
            v[4] = b.x; v[5] = b.y; v[6] = b.z; v[7] = b.w;
        }
        if (APPLY) {
            float4 sc0 = *(const float4*)(ssc + kq);
            float4 sc1 = *(const float4*)(ssc + kq + 4);
            float4 sh0 = *(const float4*)(ssh + kq);
            float4 sh1 = *(const float4*)(ssh + kq + 4);
            float sc[8] = {sc0.x, sc0.y, sc0.z, sc0.w, sc1.x, sc1.y, sc1.z, sc1.w};
            float sh[8] = {sh0.x, sh0.y, sh0.z, sh0.w, sh1.x, sh1.y, sh1.z, sh1.w};
            #pragma unroll
            for (int j = 0; j < 8; j++) {
                v[j] = fmaf(v[j], sc[j], sh[j]);
                if (RELU) v[j] = fmaxf(v[j], 0.0f);
            }
        }
        #pragma unroll
        for (int j = 0; j < 8; j++) xb[j] = f2bf(v[j]);

        #pragma unroll
        for (int nf = 0; nf < 4; nf++) {
            bf16x8 wa = *(const bf16x8*)(Wb + (size_t)(bn + nf * 16 + l16) * D + kq);
            acc[nf] = __builtin_amdgcn_mfma_f32_16x16x32_bf16(wa, xb, acc[nf], 0, 0, 0);
        }
    }

    #pragma unroll
    for (int nf = 0; nf < 4; nf++) {
        const int nb = bn + nf * 16 + q * 4;
        float4 b4 = *(const float4*)(bias + nb);
        short4 o;
        o.x = f2bf(acc[nf][0] + b4.x);
        o.y = f2bf(acc[nf][1] + b4.y);
        o.z = f2bf(acc[nf][2] + b4.z);
        o.w = f2bf(acc[nf][3] + b4.w);
        *(short4*)(Hb + (size_t)mrow * D + nb) = o;
    }
}

// ------- G[r,:] = sum_j w * Hb[idx,:] — 1 row/wave, 16-wide gather; LAST: fp32 out -------
template <bool LAST>
__global__ __launch_bounds__(256) void aggregate_bf16(const int* __restrict__ nbr_idx,
                                                      const float* __restrict__ nbr_w,
                                                      const int* __restrict__ deg,
                                                      const unsigned short* __restrict__ Hb,
                                                      unsigned short* __restrict__ Gb,
                                                      float* __restrict__ G,
                                                      float* __restrict__ psum,
                                                      float* __restrict__ psumsq) {
    const int wave = threadIdx.x >> 6;
    const int lane = threadIdx.x & 63;
    const int ch = lane * 4;
    const int r = blockIdx.x * 4 + wave;

    int dg = deg[r]; if (dg > MAX_DEG) dg = MAX_DEG;
    const int* idx = nbr_idx + (size_t)r * MAX_DEG;
    const float* wt = nbr_w + (size_t)r * MAX_DEG;
    float4 A = make_float4(0.f, 0.f, 0.f, 0.f);
    int j = 0;
    for (; j + 16 <= dg; j += 16) {          // 16 independent gathers in flight
        int4 c0 = *(const int4*)(idx + j);
        int4 c1 = *(const int4*)(idx + j + 4);
        int4 c2 = *(const int4*)(idx + j + 8);
        int4 c3 = *(const int4*)(idx + j + 12);
        float4 w0 = *(const float4*)(wt + j);
        float4 w1 = *(const float4*)(wt + j + 4);
        float4 w2 = *(const float4*)(wt + j + 8);
        float4 w3 = *(const float4*)(wt + j + 12);
        ushort4 u0 = *(const ushort4*)(Hb + (size_t)c0.x * D + ch);
        ushort4 u1 = *(const ushort4*)(Hb + (size_t)c0.y * D + ch);
        ushort4 u2 = *(const ushort4*)(Hb + (size_t)c0.z * D + ch);
        ushort4 u3 = *(const ushort4*)(Hb + (size_t)c0.w * D + ch);
        ushort4 u4 = *(const ushort4*)(Hb + (size_t)c1.x * D + ch);
        ushort4 u5 = *(const ushort4*)(Hb + (size_t)c1.y * D + ch);
        ushort4 u6 = *(const ushort4*)(Hb + (size_t)c1.z * D + ch);
        ushort4 u7 = *(const ushort4*)(Hb + (size_t)c1.w * D + ch);
        ushort4 u8 = *(const ushort4*)(Hb + (size_t)c2.x * D + ch);
        ushort4 u9 = *(const ushort4*)(Hb + (size_t)c2.y * D + ch);
        ushort4 ua = *(const ushort4*)(Hb + (size_t)c2.z * D + ch);
        ushort4 ub = *(const ushort4*)(Hb + (size_t)c2.w * D + ch);
        ushort4 uc = *(const ushort4*)(Hb + (size_t)c3.x * D + ch);
        ushort4 ud = *(const ushort4*)(Hb + (size_t)c3.y * D + ch);
        ushort4 ue = *(const ushort4*)(Hb + (size_t)c3.z * D + ch);
        ushort4 uf = *(const ushort4*)(Hb + (size_t)c3.w * D + ch);
        A.x = fmaf(w0.x, bf2f(u0.x), A.x); A.y = fmaf(w0.x, bf2f(u0.y), A.y);
        A.z = fmaf(w0.x, bf2f(u0.z), A.z); A.w = fmaf(w0.x, bf2f(u0.w), A.w);
        A.x = fmaf(w0.y, bf2f(u1.x), A.x); A.y = fmaf(w0.y, bf2f(u1.y), A.y);
        A.z = fmaf(w0.y, bf2f(u1.z), A.z); A.w = fmaf(w0.y, bf2f(u1.w), A.w);
        A.x = fmaf(w0.z, bf2f(u2.x), A.x); A.y = fmaf(w0.z, bf2f(u2.y), A.y);
        A.z = fmaf(w0.z, bf2f(u2.z), A.z); A.w = fmaf(w0.z, bf2f(u2.w), A.w);
        A.x = fmaf(w0.w, bf2f(u3.x), A.x); A.y = fmaf(w0.w, bf2f(u3.y), A.y);
        A.z = fmaf(w0.w, bf2f(u3.z), A.z); A.w = fmaf(w0.w, bf2f(u3.w), A.w);
        A.x = fmaf(w1.x, bf2f(u4.x), A.x); A.y = fmaf(w1.x, bf2f(u4.y), A.y);
        A.z = fmaf(w1.x, bf2f(u4.z), A.z); A.w = fmaf(w1.x, bf2f(u4.w), A.w);
        A.x = fmaf(w1.y, bf2f(u5.x), A.x); A.y = fmaf(w1.y, bf2f(u5.y), A.y);
        A.z = fmaf(w1.y, bf2f(u5.z), A.z); A.w = fmaf(w1.y, bf2f(u5.w), A.w);
        A.x = fmaf(w1.z, bf2f(u6.x), A.x); A.y = fmaf(w1.z, bf2f(u6.y), A.y);
        A.z = fmaf(w1.z, bf2f(u6.z), A.z); A.w = fmaf(w1.z, bf2f(u6.w), A.w);
        A.x = fmaf(w1.w, bf2f(u7.x), A.x); A.y = fmaf(w1.w, bf2f(u7.y), A.y);
        A.z = fmaf(w1.w, bf2f(u7.z), A.z); A.w = fmaf(w1.w, bf2f(u7.w), A.w);
        A.x = fmaf(w2.x, bf2f(u8.x), A.x); A.y = fmaf(w2.x, bf2f(u8.y), A.y);
        A.z = fmaf(w2.x, bf2f(u8.z), A.z); A.w = fmaf(w2.x, bf2f(u8.w), A.w);
        A.x = fmaf(w2.y, bf2f(u9.x), A.x); A.y = fmaf(w2.y, bf2f(u9.y), A.y);
        A.z = fmaf(w2.y, bf2f(u9.z), A.z); A.w = fmaf(w2.y, bf2f(u9.w), A.w);
        A.x = fmaf(w2.z, bf2f(ua.x), A.x); A.y = fmaf(w2.z, bf2f(ua.y), A.y);
        A.z = fmaf(w2.z, bf2f(ua.z), A.z); A.w = fmaf(w2.z, bf2f(ua.w), A.w);
        A.x = fmaf(w2.w, bf2f(ub.x), A.x); A.y = fmaf(w2.w, bf2f(ub.y), A.y);
        A.z = fmaf(w2.w, bf2f(ub.z), A.z); A.w = fmaf(w2.w, bf2f(ub.w), A.w);
        A.x = fmaf(w3.x, bf2f(uc.x), A.x); A.y = fmaf(w3.x, bf2f(uc.y), A.y);
        A.z = fmaf(w3.x, bf2f(uc.z), A.z); A.w = fmaf(w3.x, bf2f(uc.w), A.w);
        A.x = fmaf(w3.y, bf2f(ud.x), A.x); A.y = fmaf(w3.y, bf2f(ud.y), A.y);
        A.z = fmaf(w3.y, bf2f(ud.z), A.z); A.w = fmaf(w3.y, bf2f(ud.w), A.w);
        A.x = fmaf(w3.z, bf2f(ue.x), A.x); A.y = fmaf(w3.z, bf2f(ue.y), A.y);
        A.z = fmaf(w3.z, bf2f(ue.z), A.z); A.w = fmaf(w3.z, bf2f(ue.w), A.w);
        A.x = fmaf(w3.w, bf2f(uf.x), A.x); A.y = fmaf(w3.w, bf2f(uf.y), A.y);
        A.z = fmaf(w3.w, bf2f(uf.z), A.z); A.w = fmaf(w3.w, bf2f(uf.w), A.w);
    }
    for (; j + 4 <= dg; j += 4) {
        int4 c0 = *(const int4*)(idx + j);
        float4 w0 = *(const float4*)(wt + j);
        ushort4 u0 = *(const ushort4*)(Hb + (size_t)c0.x * D + ch);
        ushort4 u1 = *(const ushort4*)(Hb + (size_t)c0.y * D + ch);
        ushort4 u2 = *(const ushort4*)(Hb + (size_t)c0.z * D + ch);
        ushort4 u3 = *(const ushort4*)(Hb + (size_t)c0.w * D + ch);
        A.x = fmaf(w0.x, bf2f(u0.x), A.x); A.y = fmaf(w0.x, bf2f(u0.y), A.y);
        A.z = fmaf(w0.x, bf2f(u0.z), A.z); A.w = fmaf(w0.x, bf2f(u0.w), A.w);
        A.x = fmaf(w0.y, bf2f(u1.x), A.x); A.y = fmaf(w0.y, bf2f(u1.y), A.y);
        A.z = fmaf(w0.y, bf2f(u1.z), A.z); A.w = fmaf(w0.y, bf2f(u1.w), A.w);
        A.x = fmaf(w0.z, bf2f(u2.x), A.x); A.y = fmaf(w0.z, bf2f(u2.y), A.y);
        A.z = fmaf(w0.z, bf2f(u2.z), A.z); A.w = fmaf(w0.z, bf2f(u2.w), A.w);
        A.x = fmaf(w0.w, bf2f(u3.x), A.x); A.y = fmaf(w0.w, bf2f(u3.y), A.y);
        A.z = fmaf(w0.w, bf2f(u3.z), A.z); A.w = fmaf(w0.w, bf2f(u3.w), A.w);
    }
    for (; j < dg; j++) {
        int c = idx[j];
        float w = wt[j];
        ushort4 u = *(const ushort4*)(Hb + (size_t)c * D + ch);
        A.x = fmaf(w, bf2f(u.x), A.x); A.y = fmaf(w, bf2f(u.y), A.y);
        A.z = fmaf(w, bf2f(u.z), A.z); A.w = fmaf(w, bf2f(u.w), A.w);
    }
    if (LAST) {
        *(float4*)(G + (size_t)r * D + ch) = A;
    } else {
        short4 o = {f2bf(A.x), f2bf(A.y), f2bf(A.z), f2bf(A.w)};
        *(short4*)(Gb + (size_t)r * D + ch) = o;
    }

    // ---- block-level BN partial sums (fp32, pre-rounding) ----
    __shared__ float ls[4][256], lss[4][256];
    ls[wave][ch] = A.x; ls[wave][ch + 1] = A.y; ls[wave][ch + 2] = A.z; ls[wave][ch + 3] = A.w;
    lss[wave][ch] = A.x * A.x; lss[wave][ch + 1] = A.y * A.y;
    lss[wave][ch + 2] = A.z * A.z; lss[wave][ch + 3] = A.w * A.w;
    __syncthreads();
    const int t = threadIdx.x;
    psum[blockIdx.x * 256 + t] = ls[0][t] + ls[1][t] + ls[2][t] + ls[3][t];
    psumsq[blockIdx.x * 256 + t] = lss[0][t] + lss[1][t] + lss[2][t] + lss[3][t];
}

// ------- stage-1 partial reduction: 2048 rows -> 128 rows (coalesced, parallel) -------
__global__ __launch_bounds__(256) void reduce_partials(const float* __restrict__ psum,
                                                       const float* __restrict__ psumsq,
                                                       float* __restrict__ psum2,
                                                       float* __restrict__ psumsq2) {
    const int b = blockIdx.x;       // 0..127
    const int t = threadIdx.x;
    const int rows = AGG_BLOCKS / RED_BLOCKS;   // 16
    float s = 0.0f, q = 0.0f;
    #pragma unroll
    for (int i = 0; i < rows; i++) {
        s += psum[(size_t)(b * rows + i) * 256 + t];
        q += psumsq[(size_t)(b * rows + i) * 256 + t];
    }
    psum2[b * 256 + t] = s;
    psumsq2[b * 256 + t] = q;
}

// ------- final BN apply -> fp32 d_out (no relu); finalize folded into prologue -------
__global__ __launch_bounds__(256) void bn_apply_out(const float* __restrict__ G,
                                                    const float* __restrict__ psum2,
                                                    const float* __restrict__ psq2,
                                                    const float* __restrict__ g,
                                                    const float* __restrict__ be,
                                                    float* __restrict__ Out) {
    __shared__ float ssc[256], ssh[256];
    const int tid = threadIdx.x;
    {
        float s = 0.f, q = 0.f;
        #pragma unroll 8
        for (int i = 0; i < RED_BLOCKS; i++) {
            s += psum2[i * 256 + tid];
            q += psq2[i * 256 + tid];
        }
        float mu = s * (1.0f / N_NODES);
        float var = q * (1.0f / N_NODES) - mu * mu;
        float rstd = rsqrtf(var + 1e-5f);
        float sc = g[tid] * rstd;
        ssc[tid] = sc;
        ssh[tid] = be[tid] - mu * sc;
        __syncthreads();
    }
    const int rows_per_block = 64;
    const int r0 = blockIdx.x * rows_per_block;
    const int ch = (tid & 63) * 4;
    const int rsub = tid >> 6;
    float4 sc = *(const float4*)(ssc + ch);
    float4 sh = *(const float4*)(ssh + ch);
    for (int rr = rsub; rr < rows_per_block; rr += 4) {
        const size_t off = (size_t)(r0 + rr) * D + ch;
        float4 v = *(const float4*)(G + off);
        v.x = fmaf(v.x, sc.x, sh.x);
        v.y = fmaf(v.y, sc.y, sh.y);
        v.z = fmaf(v.z, sc.z, sh.z);
        v.w = fmaf(v.w, sc.w, sh.w);
        *(float4*)(Out + off) = v;
    }
}

extern "C" void kernel_launch(void* const* d_in, const int* in_sizes, int n_in,
                              void* d_out, int out_size, void* d_ws, size_t ws_size,
                              hipStream_t stream) {
    const float* x  = (const float*)d_in[0];
    const int*   ei = (const int*)d_in[1];
    const float* W1 = (const float*)d_in[2];
    const float* b1 = (const float*)d_in[3];
    const float* W2 = (const float*)d_in[4];
    const float* b2 = (const float*)d_in[5];
    const float* W3 = (const float*)d_in[6];
    const float* b3 = (const float*)d_in[7];
    const float* g1 = (const float*)d_in[8];
    const float* be1 = (const float*)d_in[9];
    const float* g2 = (const float*)d_in[10];
    const float* be2 = (const float*)d_in[11];
    const float* g3 = (const float*)d_in[12];
    const float* be3 = (const float*)d_in[13];

    char* ws = (char*)d_ws;
    // [0, 8MB): adj bitmask; dead after build_nbrs -> reused as Hb (bf16, 4 MB)
    unsigned*       adj  = (unsigned*)ws;
    unsigned short* Hb   = (unsigned short*)ws;                      // 4 MB
    int*            deg  = (int*)(ws + (8 << 20));                   // 32 KB (zeroed)
    float*          psum2= (float*)(ws + (8 << 20) + (64 << 10));    // 128 KB
    float*          psq2 = (float*)(ws + (8 << 20) + (192 << 10));   // 128 KB
    unsigned short* Wb1  = (unsigned short*)(ws + (8 << 20) + (320 << 10));
    unsigned short* Wb2  = (unsigned short*)(ws + (8 << 20) + (448 << 10));
    unsigned short* Wb3  = (unsigned short*)(ws + (8 << 20) + (576 << 10));
    float*          psum = (float*)(ws + (9 << 20));                 // 2 MB
    float*          psq  = (float*)(ws + (11 << 20));                // 2 MB
    int*            nbr_idx = (int*)  (ws + (13 << 20));             // 4 MB
    float*          nbr_w   = (float*)(ws + (17 << 20));             // 4 MB
    float*          G       = (float*)(ws + (21 << 20));             // 8 MB (fp32, layer 3)
    unsigned short* Gb      = (unsigned short*)(ws + (21 << 20));    // 4 MB (bf16, layers 1-2)

    // zero adj + deg in one fill
    hipMemsetAsync(ws, 0, (8 << 20) + (32 << 10), stream);

    build_adj<<<(N_EDGES + N_NODES + 255) / 256, 256, 0, stream>>>(ei, adj, deg);
    build_nbrs<<<N_NODES + 768, 256, 0, stream>>>(adj, deg, nbr_idx, nbr_w,
                                                  W1, W2, W3, Wb1, Wb2, Wb3);

    dim3 ggrid(D / 64, N_NODES / 64);   // 4 x 128 = 512 blocks

    // ---- Layer 1
    gemm_mfma<false, false, false><<<ggrid, 256, 0, stream>>>(x, nullptr, nullptr, nullptr,
                                                              nullptr, Wb1, b1, Hb);
    aggregate_bf16<false><<<AGG_BLOCKS, 256, 0, stream>>>(nbr_idx, nbr_w, deg, Hb, Gb, nullptr,
                                                          psum, psq);
    reduce_partials<<<RED_BLOCKS, 256, 0, stream>>>(psum, psq, psum2, psq2);

    // ---- Layer 2 (BN1 finalize + apply + relu fused into gemm, bf16 X)
    gemm_mfma<true, true, true><<<ggrid, 256, 0, stream>>>(Gb, psum2, psq2, g1, be1, Wb2, b2, Hb);
    aggregate_bf16<false><<<AGG_BLOCKS, 256, 0, stream>>>(nbr_idx, nbr_w, deg, Hb, Gb, nullptr,
                                                          psum, psq);
    reduce_partials<<<RED_BLOCKS, 256, 0, stream>>>(psum, psq, psum2, psq2);

    // ---- Layer 3 (BN2 finalize + apply + relu fused into gemm, bf16 X)
    gemm_mfma<true, true, true><<<ggrid, 256, 0, stream>>>(Gb, psum2, psq2, g2, be2, Wb3, b3, Hb);
    aggregate_bf16<true><<<AGG_BLOCKS, 256, 0, stream>>>(nbr_idx, nbr_w, deg, Hb, nullptr, G,
                                                         psum, psq);
    reduce_partials<<<RED_BLOCKS, 256, 0, stream>>>(psum, psq, psum2, psq2);

    // ---- final BN3 finalize + apply -> d_out
    bn_apply_out<<<N_NODES / 64, 256, 0, stream>>>(G, psum2, psq2, g3, be3, (float*)d_out);
}

// Round 11
// 242.525 us; speedup vs baseline: 1.0388x; 1.0388x over previous
//
#include <hip/hip_runtime.h>

#define N_NODES 8192
#define N_EDGES 262144
#define D 256
#define ADJ_WORDS 256     // 8192 bits per row / 32
#define MAX_DEG 128       // Poisson(33): P(deg>128) ~ 1e-40
#define AGG_BLOCKS 2048   // 4 waves/block, ONE row per wave -> 8192 waves, 8/SIMD
#define RED_BLOCKS 128    // partial-reduction stage-1 blocks (2048 -> 128 rows)

typedef __attribute__((ext_vector_type(8))) short bf16x8;
typedef __attribute__((ext_vector_type(4))) float f32x4;

__device__ __forceinline__ short f2bf(float f) {
    unsigned u = __builtin_bit_cast(unsigned, f);
    u += 0x7fffu + ((u >> 16) & 1);   // round to nearest even
    return (short)(u >> 16);
}
__device__ __forceinline__ float bf2f(unsigned short u) {
    return __builtin_bit_cast(float, ((unsigned)u) << 16);
}

// ---------------- adjacency build: set-semantics bitmask + exact degree ----------------
__global__ void build_adj(const int* __restrict__ ei, unsigned* __restrict__ adj,
                          int* __restrict__ deg) {
    int i = blockIdx.x * blockDim.x + threadIdx.x;
    int r, c;
    if (i < N_EDGES) {
        r = ei[i];
        c = ei[N_EDGES + i];
    } else if (i < N_EDGES + N_NODES) {
        r = i - N_EDGES;          // self loop
        c = r;
    } else {
        return;
    }
    unsigned bit = 1u << (c & 31);
    unsigned old = atomicOr(&adj[r * ADJ_WORDS + (c >> 5)], bit);
    if (!(old & bit)) atomicAdd(&deg[r], 1);   // count only newly-set bits (set semantics)
}

// ------- bitmask -> neighbor list (idx + weight, dinv inline); tail blocks: W->bf16 -------
__global__ __launch_bounds__(256) void build_nbrs(const unsigned* __restrict__ adj,
                                                  const int* __restrict__ deg,
                                                  int* __restrict__ nbr_idx,
                                                  float* __restrict__ nbr_w,
                                                  const float* __restrict__ W1,
                                                  const float* __restrict__ W2,
                                                  const float* __restrict__ W3,
                                                  unsigned short* __restrict__ Wb1,
                                                  unsigned short* __restrict__ Wb2,
                                                  unsigned short* __restrict__ Wb3) {
    if (blockIdx.x >= N_NODES) {   // weight-conversion tail blocks
        int i = (blockIdx.x - N_NODES) * 256 + threadIdx.x;
        int which = i >> 16, j = i & 65535;
        const float* src = which == 0 ? W1 : which == 1 ? W2 : W3;
        unsigned short* dst = which == 0 ? Wb1 : which == 1 ? Wb2 : Wb3;
        dst[j] = (unsigned short)f2bf(src[j]);
        return;
    }
    const int r = blockIdx.x;
    const int t = threadIdx.x;
    const int lane = t & 63, wave = t >> 6;
    unsigned m = adj[r * ADJ_WORDS + t];
    int cnt = __popc(m);
    int x = cnt;
    #pragma unroll
    for (int off = 1; off < 64; off <<= 1) {
        int v = __shfl_up(x, off, 64);
        if (lane >= off) x += v;
    }
    __shared__ int wtot[4];
    if (lane == 63) wtot[wave] = x;
    __syncthreads();
    int woff = 0;
    #pragma unroll
    for (int w = 0; w < 4; w++) woff += (w < wave) ? wtot[w] : 0;
    int base = woff + x - cnt;       // exclusive prefix
    const float dr = rsqrtf((float)deg[r]);   // deg >= 1 (self loop)
    int* oi = nbr_idx + (size_t)r * MAX_DEG;
    float* ow = nbr_w + (size_t)r * MAX_DEG;
    while (m) {
        int b = __ffs(m) - 1;
        m &= m - 1;
        int c = (t << 5) + b;
        if (base < MAX_DEG) {
            oi[base] = c;
            ow[base] = dr * rsqrtf((float)deg[c]);
        }
        base++;
    }
}

// -------- Hb(bf16) = bnapply(X) @ W^T + b  (MFMA 16x16x32 bf16) --------
// 128-row M-tile (256 blocks — prologue cost amortized; R10's 64-row tile regressed).
// BN finalize folded in (APPLY): reduce psum2/psq2 (128 rows) -> scale/shift in LDS.
// XBF16: X is bf16 (inter-layer Gb). A = W (n rows), B = X (m cols):
// C/D col(lane&15)=m, row(q*4+reg)=n -> 8B packed bf16 stores.
template <bool APPLY, bool RELU, bool XBF16>
__global__ __launch_bounds__(256) void gemm_mfma(const void* __restrict__ Xsrc,
                                                 const float* __restrict__ psum2,
                                                 const float* __restrict__ psq2,
                                                 const float* __restrict__ g,
                                                 const float* __restrict__ be,
                                                 const unsigned short* __restrict__ Wb,
                                                 const float* __restrict__ bias,
                                                 unsigned short* __restrict__ Hb) {
    __shared__ float ssc[256], ssh[256];
    const int tid = threadIdx.x;
    if (APPLY) {
        float s = 0.f, q = 0.f;
        #pragma unroll 8
        for (int i = 0; i < RED_BLOCKS; i++) {
            s += psum2[i * 256 + tid];
            q += psq2[i * 256 + tid];
        }
        float mu = s * (1.0f / N_NODES);
        float var = q * (1.0f / N_NODES) - mu * mu;
        float rstd = rsqrtf(var + 1e-5f);
        float sc = g[tid] * rstd;
        ssc[tid] = sc;
        ssh[tid] = be[tid] - mu * sc;
        __syncthreads();
    }

    const int bn = blockIdx.x * 64;           // output-channel tile
    const int bm = blockIdx.y * 128;          // node tile
    const int wave = tid >> 6, lane = tid & 63;
    const int l16 = lane & 15, q = lane >> 4;
    const int mrow0 = bm + wave * 32;

    f32x4 acc[2][4];
    #pragma unroll
    for (int i = 0; i < 2; i++)
        #pragma unroll
        for (int j = 0; j < 4; j++) acc[i][j] = (f32x4){0.f, 0.f, 0.f, 0.f};

    for (int k0 = 0; k0 < D; k0 += 32) {
        const int kq = k0 + q * 8;
        bf16x8 xb[2];
        float4 sc0, sc1, sh0, sh1;
        if (APPLY) {
            sc0 = *(const float4*)(ssc + kq);
            sc1 = *(const float4*)(ssc + kq + 4);
            sh0 = *(const float4*)(ssh + kq);
            sh1 = *(const float4*)(ssh + kq + 4);
        }
        #pragma unroll
        for (int mf = 0; mf < 2; mf++) {
            const int m = mrow0 + mf * 16 + l16;
            float v[8];
            if (XBF16) {
                bf16x8 xr = *(const bf16x8*)((const unsigned short*)Xsrc + (size_t)m * D + kq);
                #pragma unroll
                for (int j = 0; j < 8; j++) v[j] = bf2f((unsigned short)xr[j]);
            } else {
                const float* xr = (const float*)Xsrc + (size_t)m * D + kq;
                float4 a = *(const float4*)xr;
                float4 b = *(const float4*)(xr + 4);
                v[0] = a.x; v[1] = a.y; v[2] = a.z; v[3] = a.w;
                v[4] = b.x; v[5] = b.y; v[6] = b.z; v[7] = b.w;
            }
            if (APPLY) {
                float sc[8] = {sc0.x, sc0.y, sc0.z, sc0.w, sc1.x, sc1.y, sc1.z, sc1.w};
                float sh[8] = {sh0.x, sh0.y, sh0.z, sh0.w, sh1.x, sh1.y, sh1.z, sh1.w};
                #pragma unroll
                for (int j = 0; j < 8; j++) {
                    v[j] = fmaf(v[j], sc[j], sh[j]);
                    if (RELU) v[j] = fmaxf(v[j], 0.0f);
                }
            }
            #pragma unroll
            for (int j = 0; j < 8; j++) xb[mf][j] = f2bf(v[j]);
        }
        #pragma unroll
        for (int nf = 0; nf < 4; nf++) {
            bf16x8 wa = *(const bf16x8*)(Wb + (size_t)(bn + nf * 16 + l16) * D + kq);
            #pragma unroll
            for (int mf = 0; mf < 2; mf++)
                acc[mf][nf] = __builtin_amdgcn_mfma_f32_16x16x32_bf16(wa, xb[mf], acc[mf][nf], 0, 0, 0);
        }
    }

    #pragma unroll
    for (int mf = 0; mf < 2; mf++) {
        const int m = mrow0 + mf * 16 + l16;
        #pragma unroll
        for (int nf = 0; nf < 4; nf++) {
            const int nb = bn + nf * 16 + q * 4;
            float4 b4 = *(const float4*)(bias + nb);
            short4 o;
            o.x = f2bf(acc[mf][nf][0] + b4.x);
            o.y = f2bf(acc[mf][nf][1] + b4.y);
            o.z = f2bf(acc[mf][nf][2] + b4.z);
            o.w = f2bf(acc[mf][nf][3] + b4.w);
            *(short4*)(Hb + (size_t)m * D + nb) = o;
        }
    }
}

// ------- G[r,:] = sum_j w * Hb[idx,:] — 1 row/wave, 16-wide gather; LAST: fp32 out -------
template <bool LAST>
__global__ __launch_bounds__(256) void aggregate_bf16(const int* __restrict__ nbr_idx,
                                                      const float* __restrict__ nbr_w,
                                                      const int* __restrict__ deg,
                                                      const unsigned short* __restrict__ Hb,
                                                      unsigned short* __restrict__ Gb,
                                                      float* __restrict__ G,
                                                      float* __restrict__ psum,
                                                      float* __restrict__ psumsq) {
    const int wave = threadIdx.x >> 6;
    const int lane = threadIdx.x & 63;
    const int ch = lane * 4;
    const int r = blockIdx.x * 4 + wave;

    int dg = deg[r]; if (dg > MAX_DEG) dg = MAX_DEG;
    const int* idx = nbr_idx + (size_t)r * MAX_DEG;
    const float* wt = nbr_w + (size_t)r * MAX_DEG;
    float4 A = make_float4(0.f, 0.f, 0.f, 0.f);
    int j = 0;
    for (; j + 16 <= dg; j += 16) {          // 16 independent gathers in flight
        int4 c0 = *(const int4*)(idx + j);
        int4 c1 = *(const int4*)(idx + j + 4);
        int4 c2 = *(const int4*)(idx + j + 8);
        int4 c3 = *(const int4*)(idx + j + 12);
        float4 w0 = *(const float4*)(wt + j);
        float4 w1 = *(const float4*)(wt + j + 4);
        float4 w2 = *(const float4*)(wt + j + 8);
        float4 w3 = *(const float4*)(wt + j + 12);
        ushort4 u0 = *(const ushort4*)(Hb + (size_t)c0.x * D + ch);
        ushort4 u1 = *(const ushort4*)(Hb + (size_t)c0.y * D + ch);
        ushort4 u2 = *(const ushort4*)(Hb + (size_t)c0.z * D + ch);
        ushort4 u3 = *(const ushort4*)(Hb + (size_t)c0.w * D + ch);
        ushort4 u4 = *(const ushort4*)(Hb + (size_t)c1.x * D + ch);
        ushort4 u5 = *(const ushort4*)(Hb + (size_t)c1.y * D + ch);
        ushort4 u6 = *(const ushort4*)(Hb + (size_t)c1.z * D + ch);
        ushort4 u7 = *(const ushort4*)(Hb + (size_t)c1.w * D + ch);
        ushort4 u8 = *(const ushort4*)(Hb + (size_t)c2.x * D + ch);
        ushort4 u9 = *(const ushort4*)(Hb + (size_t)c2.y * D + ch);
        ushort4 ua = *(const ushort4*)(Hb + (size_t)c2.z * D + ch);
        ushort4 ub = *(const ushort4*)(Hb + (size_t)c2.w * D + ch);
        ushort4 uc = *(const ushort4*)(Hb + (size_t)c3.x * D + ch);
        ushort4 ud = *(const ushort4*)(Hb + (size_t)c3.y * D + ch);
        ushort4 ue = *(const ushort4*)(Hb + (size_t)c3.z * D + ch);
        ushort4 uf = *(const ushort4*)(Hb + (size_t)c3.w * D + ch);
        A.x = fmaf(w0.x, bf2f(u0.x), A.x); A.y = fmaf(w0.x, bf2f(u0.y), A.y);
        A.z = fmaf(w0.x, bf2f(u0.z), A.z); A.w = fmaf(w0.x, bf2f(u0.w), A.w);
        A.x = fmaf(w0.y, bf2f(u1.x), A.x); A.y = fmaf(w0.y, bf2f(u1.y), A.y);
        A.z = fmaf(w0.y, bf2f(u1.z), A.z); A.w = fmaf(w0.y, bf2f(u1.w), A.w);
        A.x = fmaf(w0.z, bf2f(u2.x), A.x); A.y = fmaf(w0.z, bf2f(u2.y), A.y);
        A.z = fmaf(w0.z, bf2f(u2.z), A.z); A.w = fmaf(w0.z, bf2f(u2.w), A.w);
        A.x = fmaf(w0.w, bf2f(u3.x), A.x); A.y = fmaf(w0.w, bf2f(u3.y), A.y);
        A.z = fmaf(w0.w, bf2f(u3.z), A.z); A.w = fmaf(w0.w, bf2f(u3.w), A.w);
        A.x = fmaf(w1.x, bf2f(u4.x), A.x); A.y = fmaf(w1.x, bf2f(u4.y), A.y);
        A.z = fmaf(w1.x, bf2f(u4.z), A.z); A.w = fmaf(w1.x, bf2f(u4.w), A.w);
        A.x = fmaf(w1.y, bf2f(u5.x), A.x); A.y = fmaf(w1.y, bf2f(u5.y), A.y);
        A.z = fmaf(w1.y, bf2f(u5.z), A.z); A.w = fmaf(w1.y, bf2f(u5.w), A.w);
        A.x = fmaf(w1.z, bf2f(u6.x), A.x); A.y = fmaf(w1.z, bf2f(u6.y), A.y);
        A.z = fmaf(w1.z, bf2f(u6.z), A.z); A.w = fmaf(w1.z, bf2f(u6.w), A.w);
        A.x = fmaf(w1.w, bf2f(u7.x), A.x); A.y = fmaf(w1.w, bf2f(u7.y), A.y);
        A.z = fmaf(w1.w, bf2f(u7.z), A.z); A.w = fmaf(w1.w, bf2f(u7.w), A.w);
        A.x = fmaf(w2.x, bf2f(u8.x), A.x); A.y = fmaf(w2.x, bf2f(u8.y), A.y);
        A.z = fmaf(w2.x, bf2f(u8.z), A.z); A.w = fmaf(w2.x, bf2f(u8.w), A.w);
        A.x = fmaf(w2.y, bf2f(u9.x), A.x); A.y = fmaf(w2.y, bf2f(u9.y), A.y);
        A.z = fmaf(w2.y, bf2f(u9.z), A.z); A.w = fmaf(w2.y, bf2f(u9.w), A.w);
        A.x = fmaf(w2.z, bf2f(ua.x), A.x); A.y = fmaf(w2.z, bf2f(ua.y), A.y);
        A.z = fmaf(w2.z, bf2f(ua.z), A.z); A.w = fmaf(w2.z, bf2f(ua.w), A.w);
        A.x = fmaf(w2.w, bf2f(ub.x), A.x); A.y = fmaf(w2.w, bf2f(ub.y), A.y);
        A.z = fmaf(w2.w, bf2f(ub.z), A.z); A.w = fmaf(w2.w, bf2f(ub.w), A.w);
        A.x = fmaf(w3.x, bf2f(uc.x), A.x); A.y = fmaf(w3.x, bf2f(uc.y), A.y);
        A.z = fmaf(w3.x, bf2f(uc.z), A.z); A.w = fmaf(w3.x, bf2f(uc.w), A.w);
        A.x = fmaf(w3.y, bf2f(ud.x), A.x); A.y = fmaf(w3.y, bf2f(ud.y), A.y);
        A.z = fmaf(w3.y, bf2f(ud.z), A.z); A.w = fmaf(w3.y, bf2f(ud.w), A.w);
        A.x = fmaf(w3.z, bf2f(ue.x), A.x); A.y = fmaf(w3.z, bf2f(ue.y), A.y);
        A.z = fmaf(w3.z, bf2f(ue.z), A.z); A.w = fmaf(w3.z, bf2f(ue.w), A.w);
        A.x = fmaf(w3.w, bf2f(uf.x), A.x); A.y = fmaf(w3.w, bf2f(uf.y), A.y);
        A.z = fmaf(w3.w, bf2f(uf.z), A.z); A.w = fmaf(w3.w, bf2f(uf.w), A.w);
    }
    for (; j + 4 <= dg; j += 4) {
        int4 c0 = *(const int4*)(idx + j);
        float4 w0 = *(const float4*)(wt + j);
        ushort4 u0 = *(const ushort4*)(Hb + (size_t)c0.x * D + ch);
        ushort4 u1 = *(const ushort4*)(Hb + (size_t)c0.y * D + ch);
        ushort4 u2 = *(const ushort4*)(Hb + (size_t)c0.z * D + ch);
        ushort4 u3 = *(const ushort4*)(Hb + (size_t)c0.w * D + ch);
        A.x = fmaf(w0.x, bf2f(u0.x), A.x); A.y = fmaf(w0.x, bf2f(u0.y), A.y);
        A.z = fmaf(w0.x, bf2f(u0.z), A.z); A.w = fmaf(w0.x, bf2f(u0.w), A.w);
        A.x = fmaf(w0.y, bf2f(u1.x), A.x); A.y = fmaf(w0.y, bf2f(u1.y), A.y);
        A.z = fmaf(w0.y, bf2f(u1.z), A.z); A.w = fmaf(w0.y, bf2f(u1.w), A.w);
        A.x = fmaf(w0.z, bf2f(u2.x), A.x); A.y = fmaf(w0.z, bf2f(u2.y), A.y);
        A.z = fmaf(w0.z, bf2f(u2.z), A.z); A.w = fmaf(w0.z, bf2f(u2.w), A.w);
        A.x = fmaf(w0.w, bf2f(u3.x), A.x); A.y = fmaf(w0.w, bf2f(u3.y), A.y);
        A.z = fmaf(w0.w, bf2f(u3.z), A.z); A.w = fmaf(w0.w, bf2f(u3.w), A.w);
    }
    for (; j < dg; j++) {
        int c = idx[j];
        float w = wt[j];
        ushort4 u = *(const ushort4*)(Hb + (size_t)c * D + ch);
        A.x = fmaf(w, bf2f(u.x), A.x); A.y = fmaf(w, bf2f(u.y), A.y);
        A.z = fmaf(w, bf2f(u.z), A.z); A.w = fmaf(w, bf2f(u.w), A.w);
    }
    if (LAST) {
        *(float4*)(G + (size_t)r * D + ch) = A;
    } else {
        short4 o = {f2bf(A.x), f2bf(A.y), f2bf(A.z), f2bf(A.w)};
        *(short4*)(Gb + (size_t)r * D + ch) = o;
    }

    // ---- block-level BN partial sums (fp32, pre-rounding) ----
    __shared__ float ls[4][256], lss[4][256];
    ls[wave][ch] = A.x; ls[wave][ch + 1] = A.y; ls[wave][ch + 2] = A.z; ls[wave][ch + 3] = A.w;
    lss[wave][ch] = A.x * A.x; lss[wave][ch + 1] = A.y * A.y;
    lss[wave][ch + 2] = A.z * A.z; lss[wave][ch + 3] = A.w * A.w;
    __syncthreads();
    const int t = threadIdx.x;
    psum[blockIdx.x * 256 + t] = ls[0][t] + ls[1][t] + ls[2][t] + ls[3][t];
    psumsq[blockIdx.x * 256 + t] = lss[0][t] + lss[1][t] + lss[2][t] + lss[3][t];
}

// ------- stage-1 partial reduction: 2048 rows -> 128 rows (coalesced, parallel) -------
__global__ __launch_bounds__(256) void reduce_partials(const float* __restrict__ psum,
                                                       const float* __restrict__ psumsq,
                                                       float* __restrict__ psum2,
                                                       float* __restrict__ psumsq2) {
    const int b = blockIdx.x;       // 0..127
    const int t = threadIdx.x;
    const int rows = AGG_BLOCKS / RED_BLOCKS;   // 16
    float s = 0.0f, q = 0.0f;
    #pragma unroll
    for (int i = 0; i < rows; i++) {
        s += psum[(size_t)(b * rows + i) * 256 + t];
        q += psumsq[(size_t)(b * rows + i) * 256 + t];
    }
    psum2[b * 256 + t] = s;
    psumsq2[b * 256 + t] = q;
}

// ------- final BN apply -> fp32 d_out (no relu); finalize folded into prologue -------
__global__ __launch_bounds__(256) void bn_apply_out(const float* __restrict__ G,
                                                    const float* __restrict__ psum2,
                                                    const float* __restrict__ psq2,
                                                    const float* __restrict__ g,
                                                    const float* __restrict__ be,
                                                    float* __restrict__ Out) {
    __shared__ float ssc[256], ssh[256];
    const int tid = threadIdx.x;
    {
        float s = 0.f, q = 0.f;
        #pragma unroll 8
        for (int i = 0; i < RED_BLOCKS; i++) {
            s += psum2[i * 256 + tid];
            q += psq2[i * 256 + tid];
        }
        float mu = s * (1.0f / N_NODES);
        float var = q * (1.0f / N_NODES) - mu * mu;
        float rstd = rsqrtf(var + 1e-5f);
        float sc = g[tid] * rstd;
        ssc[tid] = sc;
        ssh[tid] = be[tid] - mu * sc;
        __syncthreads();
    }
    const int rows_per_block = 64;
    const int r0 = blockIdx.x * rows_per_block;
    const int ch = (tid & 63) * 4;
    const int rsub = tid >> 6;
    float4 sc = *(const float4*)(ssc + ch);
    float4 sh = *(const float4*)(ssh + ch);
    for (int rr = rsub; rr < rows_per_block; rr += 4) {
        const size_t off = (size_t)(r0 + rr) * D + ch;
        float4 v = *(const float4*)(G + off);
        v.x = fmaf(v.x, sc.x, sh.x);
        v.y = fmaf(v.y, sc.y, sh.y);
        v.z = fmaf(v.z, sc.z, sh.z);
        v.w = fmaf(v.w, sc.w, sh.w);
        *(float4*)(Out + off) = v;
    }
}

extern "C" void kernel_launch(void* const* d_in, const int* in_sizes, int n_in,
                              void* d_out, int out_size, void* d_ws, size_t ws_size,
                              hipStream_t stream) {
    const float* x  = (const float*)d_in[0];
    const int*   ei = (const int*)d_in[1];
    const float* W1 = (const float*)d_in[2];
    const float* b1 = (const float*)d_in[3];
    const float* W2 = (const float*)d_in[4];
    const float* b2 = (const float*)d_in[5];
    const float* W3 = (const float*)d_in[6];
    const float* b3 = (const float*)d_in[7];
    const float* g1 = (const float*)d_in[8];
    const float* be1 = (const float*)d_in[9];
    const float* g2 = (const float*)d_in[10];
    const float* be2 = (const float*)d_in[11];
    const float* g3 = (const float*)d_in[12];
    const float* be3 = (const float*)d_in[13];

    char* ws = (char*)d_ws;
    // [0, 8MB): adj bitmask; dead after build_nbrs -> reused as Hb (bf16, 4 MB)
    unsigned*       adj  = (unsigned*)ws;
    unsigned short* Hb   = (unsigned short*)ws;                      // 4 MB
    int*            deg  = (int*)(ws + (8 << 20));                   // 32 KB (zeroed)
    float*          psum2= (float*)(ws + (8 << 20) + (64 << 10));    // 128 KB
    float*          psq2 = (float*)(ws + (8 << 20) + (192 << 10));   // 128 KB
    unsigned short* Wb1  = (unsigned short*)(ws + (8 << 20) + (320 << 10));
    unsigned short* Wb2  = (unsigned short*)(ws + (8 << 20) + (448 << 10));
    unsigned short* Wb3  = (unsigned short*)(ws + (8 << 20) + (576 << 10));
    float*          psum = (float*)(ws + (9 << 20));                 // 2 MB
    float*          psq  = (float*)(ws + (11 << 20));                // 2 MB
    int*            nbr_idx = (int*)  (ws + (13 << 20));             // 4 MB
    float*          nbr_w   = (float*)(ws + (17 << 20));             // 4 MB
    float*          G       = (float*)(ws + (21 << 20));             // 8 MB (fp32, layer 3)
    unsigned short* Gb      = (unsigned short*)(ws + (21 << 20));    // 4 MB (bf16, layers 1-2)

    // zero adj + deg in one fill
    hipMemsetAsync(ws, 0, (8 << 20) + (32 << 10), stream);

    build_adj<<<(N_EDGES + N_NODES + 255) / 256, 256, 0, stream>>>(ei, adj, deg);
    build_nbrs<<<N_NODES + 768, 256, 0, stream>>>(adj, deg, nbr_idx, nbr_w,
                                                  W1, W2, W3, Wb1, Wb2, Wb3);

    dim3 ggrid(D / 64, N_NODES / 128);   // 4 x 64 = 256 blocks (128-row M-tile)

    // ---- Layer 1
    gemm_mfma<false, false, false><<<ggrid, 256, 0, stream>>>(x, nullptr, nullptr, nullptr,
                                                              nullptr, Wb1, b1, Hb);
    aggregate_bf16<false><<<AGG_BLOCKS, 256, 0, stream>>>(nbr_idx, nbr_w, deg, Hb, Gb, nullptr,
                                                          psum, psq);
    reduce_partials<<<RED_BLOCKS, 256, 0, stream>>>(psum, psq, psum2, psq2);

    // ---- Layer 2 (BN1 finalize + apply + relu fused into gemm, bf16 X)
    gemm_mfma<true, true, true><<<ggrid, 256, 0, stream>>>(Gb, psum2, psq2, g1, be1, Wb2, b2, Hb);
    aggregate_bf16<false><<<AGG_BLOCKS, 256, 0, stream>>>(nbr_idx, nbr_w, deg, Hb, Gb, nullptr,
                                                          psum, psq);
    reduce_partials<<<RED_BLOCKS, 256, 0, stream>>>(psum, psq, psum2, psq2);

    // ---- Layer 3 (BN2 finalize + apply + relu fused into gemm, bf16 X)
    gemm_mfma<true, true, true><<<ggrid, 256, 0, stream>>>(Gb, psum2, psq2, g2, be2, Wb3, b3, Hb);
    aggregate_bf16<true><<<AGG_BLOCKS, 256, 0, stream>>>(nbr_idx, nbr_w, deg, Hb, nullptr, G,
                                                         psum, psq);
    reduce_partials<<<RED_BLOCKS, 256, 0, stream>>>(psum, psq, psum2, psq2);

    // ---- final BN3 finalize + apply -> d_out
    bn_apply_out<<<N_NODES / 64, 256, 0, stream>>>(G, psum2, psq2, g3, be3, (float*)d_out);
}

// Round 12
// 237.250 us; speedup vs baseline: 1.0619x; 1.0222x over previous
//
#include <hip/hip_runtime.h>

#define N_NODES 8192
#define N_EDGES 262144
#define D 256
#define ADJ_WORDS 256     // 8192 bits per row / 32
#define MAX_DEG 128       // Poisson(33): P(deg>128) ~ 1e-40
#define AGG_BLOCKS 2048   // 4 waves/block, ONE row per wave -> 8192 waves, 8/SIMD
#define RED_BLOCKS 128    // partial-reduction stage-1 blocks (2048 -> 128 rows)

typedef __attribute__((ext_vector_type(8))) short bf16x8;
typedef __attribute__((ext_vector_type(4))) float f32x4;

__device__ __forceinline__ short f2bf(float f) {
    unsigned u = __builtin_bit_cast(unsigned, f);
    u += 0x7fffu + ((u >> 16) & 1);   // round to nearest even
    return (short)(u >> 16);
}
__device__ __forceinline__ float bf2f(unsigned short u) {
    return __builtin_bit_cast(float, ((unsigned)u) << 16);
}

// ---------------- adjacency build: set-semantics bitmask + exact degree ----------------
__global__ void build_adj(const int* __restrict__ ei, unsigned* __restrict__ adj,
                          int* __restrict__ deg) {
    int i = blockIdx.x * blockDim.x + threadIdx.x;
    int r, c;
    if (i < N_EDGES) {
        r = ei[i];
        c = ei[N_EDGES + i];
    } else if (i < N_EDGES + N_NODES) {
        r = i - N_EDGES;          // self loop
        c = r;
    } else {
        return;
    }
    unsigned bit = 1u << (c & 31);
    unsigned old = atomicOr(&adj[r * ADJ_WORDS + (c >> 5)], bit);
    if (!(old & bit)) atomicAdd(&deg[r], 1);   // count only newly-set bits (set semantics)
}

// ------- bitmask -> neighbor list (idx + weight, dinv inline); tail blocks: W->bf16 -------
__global__ __launch_bounds__(256) void build_nbrs(const unsigned* __restrict__ adj,
                                                  const int* __restrict__ deg,
                                                  int* __restrict__ nbr_idx,
                                                  float* __restrict__ nbr_w,
                                                  const float* __restrict__ W1,
                                                  const float* __restrict__ W2,
                                                  const float* __restrict__ W3,
                                                  unsigned short* __restrict__ Wb1,
                                                  unsigned short* __restrict__ Wb2,
                                                  unsigned short* __restrict__ Wb3) {
    if (blockIdx.x >= N_NODES) {   // weight-conversion tail blocks
        int i = (blockIdx.x - N_NODES) * 256 + threadIdx.x;
        int which = i >> 16, j = i & 65535;
        const float* src = which == 0 ? W1 : which == 1 ? W2 : W3;
        unsigned short* dst = which == 0 ? Wb1 : which == 1 ? Wb2 : Wb3;
        dst[j] = (unsigned short)f2bf(src[j]);
        return;
    }
    const int r = blockIdx.x;
    const int t = threadIdx.x;
    const int lane = t & 63, wave = t >> 6;
    unsigned m = adj[r * ADJ_WORDS + t];
    int cnt = __popc(m);
    int x = cnt;
    #pragma unroll
    for (int off = 1; off < 64; off <<= 1) {
        int v = __shfl_up(x, off, 64);
        if (lane >= off) x += v;
    }
    __shared__ int wtot[4];
    if (lane == 63) wtot[wave] = x;
    __syncthreads();
    int woff = 0;
    #pragma unroll
    for (int w = 0; w < 4; w++) woff += (w < wave) ? wtot[w] : 0;
    int base = woff + x - cnt;       // exclusive prefix
    const float dr = rsqrtf((float)deg[r]);   // deg >= 1 (self loop)
    int* oi = nbr_idx + (size_t)r * MAX_DEG;
    float* ow = nbr_w + (size_t)r * MAX_DEG;
    while (m) {
        int b = __ffs(m) - 1;
        m &= m - 1;
        int c = (t << 5) + b;
        if (base < MAX_DEG) {
            oi[base] = c;
            ow[base] = dr * rsqrtf((float)deg[c]);
        }
        base++;
    }
}

// -------- Hb(bf16) = bnapply(Xsrc fp32) @ W^T + b  (MFMA 16x16x32 bf16) --------
// BN finalize folded in: APPLY blocks reduce psum2/psq2 (128 rows, prev dispatch)
// -> scale/shift in LDS. A = W (n rows), B = X (m cols): C/D col(lane&15)=m,
// row(q*4+reg)=n -> 8B packed bf16 stores.
template <bool APPLY, bool RELU>
__global__ __launch_bounds__(256) void gemm_mfma(const float* __restrict__ Xsrc,
                                                 const float* __restrict__ psum2,
                                                 const float* __restrict__ psq2,
                                                 const float* __restrict__ g,
                                                 const float* __restrict__ be,
                                                 const unsigned short* __restrict__ Wb,
                                                 const float* __restrict__ bias,
                                                 unsigned short* __restrict__ Hb) {
    __shared__ float ssc[256], ssh[256];
    const int tid = threadIdx.x;
    if (APPLY) {
        float s = 0.f, q = 0.f;
        #pragma unroll 8
        for (int i = 0; i < RED_BLOCKS; i++) {
            s += psum2[i * 256 + tid];
            q += psq2[i * 256 + tid];
        }
        float mu = s * (1.0f / N_NODES);
        float var = q * (1.0f / N_NODES) - mu * mu;
        float rstd = rsqrtf(var + 1e-5f);
        float sc = g[tid] * rstd;
        ssc[tid] = sc;
        ssh[tid] = be[tid] - mu * sc;
        __syncthreads();
    }

    const int bn = blockIdx.x * 64;           // output-channel tile
    const int bm = blockIdx.y * 128;          // node tile
    const int wave = tid >> 6, lane = tid & 63;
    const int l16 = lane & 15, q = lane >> 4;
    const int mrow0 = bm + wave * 32;

    f32x4 acc[2][4];
    #pragma unroll
    for (int i = 0; i < 2; i++)
        #pragma unroll
        for (int j = 0; j < 4; j++) acc[i][j] = (f32x4){0.f, 0.f, 0.f, 0.f};

    for (int k0 = 0; k0 < D; k0 += 32) {
        const int kq = k0 + q * 8;
        bf16x8 xb[2];
        float4 sc0, sc1, sh0, sh1;
        if (APPLY) {
            sc0 = *(const float4*)(ssc + kq);
            sc1 = *(const float4*)(ssc + kq + 4);
            sh0 = *(const float4*)(ssh + kq);
            sh1 = *(const float4*)(ssh + kq + 4);
        }
        #pragma unroll
        for (int mf = 0; mf < 2; mf++) {
            const float* xr = Xsrc + (size_t)(mrow0 + mf * 16 + l16) * D + kq;
            float4 a = *(const float4*)xr;
            float4 b = *(const float4*)(xr + 4);
            float v[8] = {a.x, a.y, a.z, a.w, b.x, b.y, b.z, b.w};
            if (APPLY) {
                float sc[8] = {sc0.x, sc0.y, sc0.z, sc0.w, sc1.x, sc1.y, sc1.z, sc1.w};
                float sh[8] = {sh0.x, sh0.y, sh0.z, sh0.w, sh1.x, sh1.y, sh1.z, sh1.w};
                #pragma unroll
                for (int j = 0; j < 8; j++) {
                    v[j] = fmaf(v[j], sc[j], sh[j]);
                    if (RELU) v[j] = fmaxf(v[j], 0.0f);
                }
            }
            #pragma unroll
            for (int j = 0; j < 8; j++) xb[mf][j] = f2bf(v[j]);
        }
        #pragma unroll
        for (int nf = 0; nf < 4; nf++) {
            bf16x8 wa = *(const bf16x8*)(Wb + (size_t)(bn + nf * 16 + l16) * D + kq);
            #pragma unroll
            for (int mf = 0; mf < 2; mf++)
                acc[mf][nf] = __builtin_amdgcn_mfma_f32_16x16x32_bf16(wa, xb[mf], acc[mf][nf], 0, 0, 0);
        }
    }

    #pragma unroll
    for (int mf = 0; mf < 2; mf++) {
        const int m = mrow0 + mf * 16 + l16;
        #pragma unroll
        for (int nf = 0; nf < 4; nf++) {
            const int nb = bn + nf * 16 + q * 4;
            float4 b4 = *(const float4*)(bias + nb);
            short4 o;
            o.x = f2bf(acc[mf][nf][0] + b4.x);
            o.y = f2bf(acc[mf][nf][1] + b4.y);
            o.z = f2bf(acc[mf][nf][2] + b4.z);
            o.w = f2bf(acc[mf][nf][3] + b4.w);
            *(short4*)(Hb + (size_t)m * D + nb) = o;
        }
    }
}

// ------- G[r,:] = sum_j w * Hb[idx,:]  — ONE row per wave, 8-wide gather unroll -------
__global__ __launch_bounds__(256) void aggregate_bf16(const int* __restrict__ nbr_idx,
                                                      const float* __restrict__ nbr_w,
                                                      const int* __restrict__ deg,
                                                      const unsigned short* __restrict__ Hb,
                                                      float* __restrict__ G,
                                                      float* __restrict__ psum,
                                                      float* __restrict__ psumsq) {
    const int wave = threadIdx.x >> 6;
    const int lane = threadIdx.x & 63;
    const int ch = lane * 4;
    const int r = blockIdx.x * 4 + wave;

    int dg = deg[r]; if (dg > MAX_DEG) dg = MAX_DEG;
    const int* idx = nbr_idx + (size_t)r * MAX_DEG;
    const float* wt = nbr_w + (size_t)r * MAX_DEG;
    float4 A = make_float4(0.f, 0.f, 0.f, 0.f);
    int j = 0;
    for (; j + 8 <= dg; j += 8) {            // 8 independent gathers in flight
        int4 c0 = *(const int4*)(idx + j);
        int4 c1 = *(const int4*)(idx + j + 4);
        float4 w0 = *(const float4*)(wt + j);
        float4 w1 = *(const float4*)(wt + j + 4);
        ushort4 u0 = *(const ushort4*)(Hb + (size_t)c0.x * D + ch);
        ushort4 u1 = *(const ushort4*)(Hb + (size_t)c0.y * D + ch);
        ushort4 u2 = *(const ushort4*)(Hb + (size_t)c0.z * D + ch);
        ushort4 u3 = *(const ushort4*)(Hb + (size_t)c0.w * D + ch);
        ushort4 u4 = *(const ushort4*)(Hb + (size_t)c1.x * D + ch);
        ushort4 u5 = *(const ushort4*)(Hb + (size_t)c1.y * D + ch);
        ushort4 u6 = *(const ushort4*)(Hb + (size_t)c1.z * D + ch);
        ushort4 u7 = *(const ushort4*)(Hb + (size_t)c1.w * D + ch);
        A.x = fmaf(w0.x, bf2f(u0.x), A.x); A.y = fmaf(w0.x, bf2f(u0.y), A.y);
        A.z = fmaf(w0.x, bf2f(u0.z), A.z); A.w = fmaf(w0.x, bf2f(u0.w), A.w);
        A.x = fmaf(w0.y, bf2f(u1.x), A.x); A.y = fmaf(w0.y, bf2f(u1.y), A.y);
        A.z = fmaf(w0.y, bf2f(u1.z), A.z); A.w = fmaf(w0.y, bf2f(u1.w), A.w);
        A.x = fmaf(w0.z, bf2f(u2.x), A.x); A.y = fmaf(w0.z, bf2f(u2.y), A.y);
        A.z = fmaf(w0.z, bf2f(u2.z), A.z); A.w = fmaf(w0.z, bf2f(u2.w), A.w);
        A.x = fmaf(w0.w, bf2f(u3.x), A.x); A.y = fmaf(w0.w, bf2f(u3.y), A.y);
        A.z = fmaf(w0.w, bf2f(u3.z), A.z); A.w = fmaf(w0.w, bf2f(u3.w), A.w);
        A.x = fmaf(w1.x, bf2f(u4.x), A.x); A.y = fmaf(w1.x, bf2f(u4.y), A.y);
        A.z = fmaf(w1.x, bf2f(u4.z), A.z); A.w = fmaf(w1.x, bf2f(u4.w), A.w);
        A.x = fmaf(w1.y, bf2f(u5.x), A.x); A.y = fmaf(w1.y, bf2f(u5.y), A.y);
        A.z = fmaf(w1.y, bf2f(u5.z), A.z); A.w = fmaf(w1.y, bf2f(u5.w), A.w);
        A.x = fmaf(w1.z, bf2f(u6.x), A.x); A.y = fmaf(w1.z, bf2f(u6.y), A.y);
        A.z = fmaf(w1.z, bf2f(u6.z), A.z); A.w = fmaf(w1.z, bf2f(u6.w), A.w);
        A.x = fmaf(w1.w, bf2f(u7.x), A.x); A.y = fmaf(w1.w, bf2f(u7.y), A.y);
        A.z = fmaf(w1.w, bf2f(u7.z), A.z); A.w = fmaf(w1.w, bf2f(u7.w), A.w);
    }
    for (; j + 4 <= dg; j += 4) {
        int4 c0 = *(const int4*)(idx + j);
        float4 w0 = *(const float4*)(wt + j);
        ushort4 u0 = *(const ushort4*)(Hb + (size_t)c0.x * D + ch);
        ushort4 u1 = *(const ushort4*)(Hb + (size_t)c0.y * D + ch);
        ushort4 u2 = *(const ushort4*)(Hb + (size_t)c0.z * D + ch);
        ushort4 u3 = *(const ushort4*)(Hb + (size_t)c0.w * D + ch);
        A.x = fmaf(w0.x, bf2f(u0.x), A.x); A.y = fmaf(w0.x, bf2f(u0.y), A.y);
        A.z = fmaf(w0.x, bf2f(u0.z), A.z); A.w = fmaf(w0.x, bf2f(u0.w), A.w);
        A.x = fmaf(w0.y, bf2f(u1.x), A.x); A.y = fmaf(w0.y, bf2f(u1.y), A.y);
        A.z = fmaf(w0.y, bf2f(u1.z), A.z); A.w = fmaf(w0.y, bf2f(u1.w), A.w);
        A.x = fmaf(w0.z, bf2f(u2.x), A.x); A.y = fmaf(w0.z, bf2f(u2.y), A.y);
        A.z = fmaf(w0.z, bf2f(u2.z), A.z); A.w = fmaf(w0.z, bf2f(u2.w), A.w);
        A.x = fmaf(w0.w, bf2f(u3.x), A.x); A.y = fmaf(w0.w, bf2f(u3.y), A.y);
        A.z = fmaf(w0.w, bf2f(u3.z), A.z); A.w = fmaf(w0.w, bf2f(u3.w), A.w);
    }
    for (; j < dg; j++) {
        int c = idx[j];
        float w = wt[j];
        ushort4 u = *(const ushort4*)(Hb + (size_t)c * D + ch);
        A.x = fmaf(w, bf2f(u.x), A.x); A.y = fmaf(w, bf2f(u.y), A.y);
        A.z = fmaf(w, bf2f(u.z), A.z); A.w = fmaf(w, bf2f(u.w), A.w);
    }
    *(float4*)(G + (size_t)r * D + ch) = A;

    // ---- block-level BN partial sums ----
    __shared__ float ls[4][256], lss[4][256];
    ls[wave][ch] = A.x; ls[wave][ch + 1] = A.y; ls[wave][ch + 2] = A.z; ls[wave][ch + 3] = A.w;
    lss[wave][ch] = A.x * A.x; lss[wave][ch + 1] = A.y * A.y;
    lss[wave][ch + 2] = A.z * A.z; lss[wave][ch + 3] = A.w * A.w;
    __syncthreads();
    const int t = threadIdx.x;
    psum[blockIdx.x * 256 + t] = ls[0][t] + ls[1][t] + ls[2][t] + ls[3][t];
    psumsq[blockIdx.x * 256 + t] = lss[0][t] + lss[1][t] + lss[2][t] + lss[3][t];
}

// ------- stage-1 partial reduction: 2048 rows -> 128 rows (coalesced, parallel) -------
__global__ __launch_bounds__(256) void reduce_partials(const float* __restrict__ psum,
                                                       const float* __restrict__ psumsq,
                                                       float* __restrict__ psum2,
                                                       float* __restrict__ psumsq2) {
    const int b = blockIdx.x;       // 0..127
    const int t = threadIdx.x;
    const int rows = AGG_BLOCKS / RED_BLOCKS;   // 16
    float s = 0.0f, q = 0.0f;
    #pragma unroll
    for (int i = 0; i < rows; i++) {
        s += psum[(size_t)(b * rows + i) * 256 + t];
        q += psumsq[(size_t)(b * rows + i) * 256 + t];
    }
    psum2[b * 256 + t] = s;
    psumsq2[b * 256 + t] = q;
}

// ------- final BN apply -> fp32 d_out (no relu); finalize folded into prologue -------
__global__ __launch_bounds__(256) void bn_apply_out(const float* __restrict__ G,
                                                    const float* __restrict__ psum2,
                                                    const float* __restrict__ psq2,
                                                    const float* __restrict__ g,
                                                    const float* __restrict__ be,
                                                    float* __restrict__ Out) {
    __shared__ float ssc[256], ssh[256];
    const int tid = threadIdx.x;
    {
        float s = 0.f, q = 0.f;
        #pragma unroll 8
        for (int i = 0; i < RED_BLOCKS; i++) {
            s += psum2[i * 256 + tid];
            q += psq2[i * 256 + tid];
        }
        float mu = s * (1.0f / N_NODES);
        float var = q * (1.0f / N_NODES) - mu * mu;
        float rstd = rsqrtf(var + 1e-5f);
        float sc = g[tid] * rstd;
        ssc[tid] = sc;
        ssh[tid] = be[tid] - mu * sc;
        __syncthreads();
    }
    // each block covers 64 rows; thread handles 4 channels (tid*4 % 256)
    const int rows_per_block = 64;
    const int r0 = blockIdx.x * rows_per_block;
    const int ch = (tid & 63) * 4;
    const int rsub = tid >> 6;      // 4 rows covered per pass by the 4 waves
    float4 sc = *(const float4*)(ssc + ch);
    float4 sh = *(const float4*)(ssh + ch);
    for (int rr = rsub; rr < rows_per_block; rr += 4) {
        const size_t off = (size_t)(r0 + rr) * D + ch;
        float4 v = *(const float4*)(G + off);
        v.x = fmaf(v.x, sc.x, sh.x);
        v.y = fmaf(v.y, sc.y, sh.y);
        v.z = fmaf(v.z, sc.z, sh.z);
        v.w = fmaf(v.w, sc.w, sh.w);
        *(float4*)(Out + off) = v;
    }
}

extern "C" void kernel_launch(void* const* d_in, const int* in_sizes, int n_in,
                              void* d_out, int out_size, void* d_ws, size_t ws_size,
                              hipStream_t stream) {
    const float* x  = (const float*)d_in[0];
    const int*   ei = (const int*)d_in[1];
    const float* W1 = (const float*)d_in[2];
    const float* b1 = (const float*)d_in[3];
    const float* W2 = (const float*)d_in[4];
    const float* b2 = (const float*)d_in[5];
    const float* W3 = (const float*)d_in[6];
    const float* b3 = (const float*)d_in[7];
    const float* g1 = (const float*)d_in[8];
    const float* be1 = (const float*)d_in[9];
    const float* g2 = (const float*)d_in[10];
    const float* be2 = (const float*)d_in[11];
    const float* g3 = (const float*)d_in[12];
    const float* be3 = (const float*)d_in[13];

    char* ws = (char*)d_ws;
    // [0, 8MB): adj bitmask; dead after build_nbrs -> reused as Hb (bf16, 4 MB)
    unsigned*       adj  = (unsigned*)ws;
    unsigned short* Hb   = (unsigned short*)ws;                      // 4 MB
    int*            deg  = (int*)(ws + (8 << 20));                   // 32 KB (zeroed)
    float*          psum2= (float*)(ws + (8 << 20) + (64 << 10));    // 128 KB
    float*          psq2 = (float*)(ws + (8 << 20) + (192 << 10));   // 128 KB
    unsigned short* Wb1  = (unsigned short*)(ws + (8 << 20) + (320 << 10));
    unsigned short* Wb2  = (unsigned short*)(ws + (8 << 20) + (448 << 10));
    unsigned short* Wb3  = (unsigned short*)(ws + (8 << 20) + (576 << 10));
    float*          psum = (float*)(ws + (9 << 20));                 // 2 MB
    float*          psq  = (float*)(ws + (11 << 20));                // 2 MB
    int*            nbr_idx = (int*)  (ws + (13 << 20));             // 4 MB
    float*          nbr_w   = (float*)(ws + (17 << 20));             // 4 MB
    float*          G       = (float*)(ws + (21 << 20));             // 8 MB

    // zero adj + deg in one fill
    hipMemsetAsync(ws, 0, (8 << 20) + (32 << 10), stream);

    build_adj<<<(N_EDGES + N_NODES + 255) / 256, 256, 0, stream>>>(ei, adj, deg);
    build_nbrs<<<N_NODES + 768, 256, 0, stream>>>(adj, deg, nbr_idx, nbr_w,
                                                  W1, W2, W3, Wb1, Wb2, Wb3);

    dim3 ggrid(D / 64, N_NODES / 128);

    // ---- Layer 1
    gemm_mfma<false, false><<<ggrid, 256, 0, stream>>>(x, nullptr, nullptr, nullptr, nullptr,
                                                       Wb1, b1, Hb);
    aggregate_bf16<<<AGG_BLOCKS, 256, 0, stream>>>(nbr_idx, nbr_w, deg, Hb, G, psum, psq);
    reduce_partials<<<RED_BLOCKS, 256, 0, stream>>>(psum, psq, psum2, psq2);

    // ---- Layer 2 (BN1 finalize + apply + relu fused into gemm)
    gemm_mfma<true, true><<<ggrid, 256, 0, stream>>>(G, psum2, psq2, g1, be1, Wb2, b2, Hb);
    aggregate_bf16<<<AGG_BLOCKS, 256, 0, stream>>>(nbr_idx, nbr_w, deg, Hb, G, psum, psq);
    reduce_partials<<<RED_BLOCKS, 256, 0, stream>>>(psum, psq, psum2, psq2);

    // ---- Layer 3 (BN2 finalize + apply + relu fused into gemm)
    gemm_mfma<true, true><<<ggrid, 256, 0, stream>>>(G, psum2, psq2, g2, be2, Wb3, b3, Hb);
    aggregate_bf16<<<AGG_BLOCKS, 256, 0, stream>>>(nbr_idx, nbr_w, deg, Hb, G, psum, psq);
    reduce_partials<<<RED_BLOCKS, 256, 0, stream>>>(psum, psq, psum2, psq2);

    // ---- final BN3 finalize + apply -> d_out
    bn_apply_out<<<N_NODES / 64, 256, 0, stream>>>(G, psum2, psq2, g3, be3, (float*)d_out);
}